// Round 6
// baseline (530.166 us; speedup 1.0000x reference)
//
#include <hip/hip_runtime.h>

#define NPTS 400000
#define KK 27
#define CC 32
#define EPSV 1e-5f
#define LSTRIDE 29   // 27 k's padded to odd stride -> conflict-free LDS access

using bf8_t = __attribute__((ext_vector_type(8))) __bf16;
using f4_t  = __attribute__((ext_vector_type(4))) float;
using us8_t = __attribute__((ext_vector_type(8))) unsigned short;

__device__ __forceinline__ unsigned short f2bf(float f) {
    unsigned int u = __float_as_uint(f);
    u += 0x7FFF + ((u >> 16) & 1u);   // RNE to bf16
    return (unsigned short)(u >> 16);
}
__device__ __forceinline__ float bf2f(unsigned short s) {
    return __uint_as_float((unsigned)s << 16);
}

// ---------------------------------------------------------------------------
// Fused conversions: blocks [0,216) transpose W1|W2 -> bf16 [k][d][c];
// remaining blocks convert x -> bf16 rows. Block 0 zeroes the BN-stat slots.
// ---------------------------------------------------------------------------
#define WBLOCKS 216  // 2*27*32*32 / 256
__global__ __launch_bounds__(256) void cvt_all(
    const float* __restrict__ x,
    const float* __restrict__ W1, const float* __restrict__ W2,
    unsigned short* __restrict__ xb,
    unsigned short* __restrict__ Wt1, unsigned short* __restrict__ Wt2,
    float* __restrict__ sums)
{
    const int bid = blockIdx.x;
    if (bid < WBLOCKS) {
        if (bid == 0) sums[threadIdx.x] = 0.f;   // zero 256 stat slots
        const int id = bid * 256 + threadIdx.x;          // < 55296
        const int which = id >= KK * CC * CC;
        const int t = which ? id - KK * CC * CC : id;
        const int k = t >> 10, d = (t >> 5) & 31, c = t & 31;
        const float* W = which ? W2 : W1;
        unsigned short* Wt = which ? Wt2 : Wt1;
        Wt[t] = f2bf(W[k * 1024 + c * CC + d]);
        return;
    }
    const size_t base = ((size_t)(bid - WBLOCKS) * 256 + threadIdx.x) * 8;
    if (base >= (size_t)NPTS * CC) return;
    // x single-use here -> nt (keep L2 for gather sets; round-3: -10% on conv)
    const f4_t v0 = __builtin_nontemporal_load((const f4_t*)(x + base));
    const f4_t v1 = __builtin_nontemporal_load((const f4_t*)(x + base + 4));
    us8_t o;
#pragma unroll
    for (int j = 0; j < 8; ++j) o[j] = f2bf(j < 4 ? v0[j] : v1[j - 4]);
    *(us8_t*)(xb + base) = o;   // re-read by conv1 gathers: keep cached
}

// ---------------------------------------------------------------------------
// conv1: gather-GEMM via MFMA, bf16 h1 output + BN stats.
// Established rounds 0-3: conv time is set by the random-gather L2-miss line
// rate (~37G lines/s chip-wide) — insensitive to occupancy (38->60%: +3%),
// ILP depth, weight volume (2x: +0%); nt-hints on single-use streams -10%.
// h1 stored as bf16 (halves conv write traffic; BN1 stats still from fp32).
// ---------------------------------------------------------------------------
__global__ __launch_bounds__(512, 6) void conv1_mfma(
    const unsigned short* __restrict__ xb,   // [N][32] bf16
    const unsigned short* __restrict__ Wt,   // [27][32(d)][32(c)] bf16
    const float* __restrict__ bias,          // [32]
    const int* __restrict__ nbr,             // [N][27]
    const int* __restrict__ mask,            // [N][27] int32 0/1
    unsigned short* __restrict__ hb,         // [N][32] bf16 out (scratch)
    float* __restrict__ sums)                // [64]: sum, sumsq
{
    __shared__ int lidx[128 * LSTRIDE];      // 14848 B
    __shared__ float rs[8][CC], rq[8][CC];   // 2048 B

    const int t = threadIdx.x;
    const int P0 = blockIdx.x * 128;         // 3125 blocks * 128 = N exactly

    const int* nb = nbr + (size_t)P0 * KK;
    const int* mb = mask + (size_t)P0 * KK;
    for (int i = t; i < 128 * KK; i += 512) {
        const int p = i / KK;
        const int k = i - p * KK;
        const int nv = __builtin_nontemporal_load(nb + i);
        const int mv = __builtin_nontemporal_load(mb + i);
        lidx[p * LSTRIDE + k] = mv ? nv : -1;
    }
    __syncthreads();

    const int wave = t >> 6;                 // 0..7
    const int lane = t & 63;
    const int m = lane & 15;
    const int q = lane >> 4;
    const int p0 = P0 + wave * 16;

    const int* rowA = lidx + (wave * 16 + m) * LSTRIDE;

    f4_t acc00 = {}, acc01 = {};

#pragma unroll
    for (int kb = 0; kb < 3; ++kb) {
        int idx[9];
#pragma unroll
        for (int j = 0; j < 9; ++j) idx[j] = rowA[kb * 9 + j];
        bf8_t A0[9];
#pragma unroll
        for (int j = 0; j < 9; ++j) {
            bf8_t t0 = {};
            if (idx[j] >= 0) t0 = *(const bf8_t*)(xb + (size_t)idx[j] * CC + q * 8);
            A0[j] = t0;
        }
#pragma unroll
        for (int j = 0; j < 9; ++j) {
            const unsigned short* wk = Wt + (kb * 9 + j) * (CC * CC) + q * 8;
            const bf8_t w0 = *(const bf8_t*)(wk + m * CC);          // d 0..15
            const bf8_t w1 = *(const bf8_t*)(wk + (m + 16) * CC);   // d 16..31
            acc00 = __builtin_amdgcn_mfma_f32_16x16x32_bf16(A0[j], w0, acc00, 0, 0, 0);
            acc01 = __builtin_amdgcn_mfma_f32_16x16x32_bf16(A0[j], w1, acc01, 0, 0, 0);
        }
    }

    // epilogue: D[row=(q*4+r)][col=m] -> point p0+q*4+r, channel m (+16)
    const float b0 = bias[m], b1 = bias[m + 16];
    float s0 = 0.f, q0 = 0.f, s1 = 0.f, q1 = 0.f;
    const int prow = p0 + q * 4;
#pragma unroll
    for (int r = 0; r < 4; ++r) {
        const float v0 = acc00[r] + b0;
        const float v1 = acc01[r] + b1;
        // stats from fp32 (pre-quantization); h1 stored bf16, nt (single
        // producer; conv2 re-fetches from L3 — protect xb in L2 now)
        __builtin_nontemporal_store(f2bf(v0), hb + (size_t)(prow + r) * CC + m);
        __builtin_nontemporal_store(f2bf(v1), hb + (size_t)(prow + r) * CC + m + 16);
        s0 += v0; q0 += v0 * v0;
        s1 += v1; q1 += v1 * v1;
    }
    s0 += __shfl_down(s0, 32, 64); s0 += __shfl_down(s0, 16, 64);
    q0 += __shfl_down(q0, 32, 64); q0 += __shfl_down(q0, 16, 64);
    s1 += __shfl_down(s1, 32, 64); s1 += __shfl_down(s1, 16, 64);
    q1 += __shfl_down(q1, 32, 64); q1 += __shfl_down(q1, 16, 64);

    if (lane < 16) {
        rs[wave][m] = s0;      rq[wave][m] = q0;
        rs[wave][m + 16] = s1; rq[wave][m + 16] = q1;
    }
    __syncthreads();
    if (t < CC) {
        float ssum = 0.f, qsum = 0.f;
#pragma unroll
        for (int w = 0; w < 8; ++w) { ssum += rs[w][t]; qsum += rq[w][t]; }
        atomicAdd(&sums[t], ssum);
        atomicAdd(&sums[CC + t], qsum);
    }
}

// ---------------------------------------------------------------------------
// conv2 with BN1+ReLU fused into the gather path (replaces the bn_relu_bf16
// kernel + one kernel boundary). Per-thread: 8 channels' (sc, sh) from sums1
// (16 VGPRs), ~5 VALU/elem on gathered data (~+3% of tile cycles — conv is
// miss-line-rate bound, so free). Masked neighbors remain exact zeros.
// ---------------------------------------------------------------------------
__global__ __launch_bounds__(512, 6) void conv2_mfma(
    const unsigned short* __restrict__ hb,   // [N][32] bf16 h1 (raw, pre-BN)
    const unsigned short* __restrict__ Wt,   // [27][32(d)][32(c)] bf16
    const float* __restrict__ bias,          // [32] (b2)
    const float* __restrict__ g1, const float* __restrict__ be1,
    const float* __restrict__ sums1,         // [64] BN1 stats
    const int* __restrict__ nbr,             // [N][27]
    const int* __restrict__ mask,            // [N][27] int32 0/1
    unsigned short* __restrict__ h2b,        // [N][32] bf16 out (scratch)
    float* __restrict__ sums)                // [64]: BN2 stats
{
    __shared__ int lidx[128 * LSTRIDE];
    __shared__ float rs[8][CC], rq[8][CC];

    const int t = threadIdx.x;
    const int P0 = blockIdx.x * 128;

    const int* nb = nbr + (size_t)P0 * KK;
    const int* mb = mask + (size_t)P0 * KK;
    for (int i = t; i < 128 * KK; i += 512) {
        const int p = i / KK;
        const int k = i - p * KK;
        const int nv = __builtin_nontemporal_load(nb + i);
        const int mv = __builtin_nontemporal_load(mb + i);
        lidx[p * LSTRIDE + k] = mv ? nv : -1;
    }
    __syncthreads();

    const int wave = t >> 6;
    const int lane = t & 63;
    const int m = lane & 15;
    const int q = lane >> 4;
    const int p0 = P0 + wave * 16;

    // BN1 affine for this lane's 8 gathered channels (c = q*8 + e)
    float sc_[8], sh_[8];
#pragma unroll
    for (int e = 0; e < 8; ++e) {
        const int c = q * 8 + e;
        const float mean = sums1[c] * (1.f / NPTS);
        const float var = sums1[CC + c] * (1.f / NPTS) - mean * mean;
        const float s = g1[c] * rsqrtf(var + EPSV);
        sc_[e] = s;
        sh_[e] = be1[c] - mean * s;
    }

    const int* rowA = lidx + (wave * 16 + m) * LSTRIDE;

    f4_t acc00 = {}, acc01 = {};

#pragma unroll
    for (int kb = 0; kb < 3; ++kb) {
        int idx[9];
#pragma unroll
        for (int j = 0; j < 9; ++j) idx[j] = rowA[kb * 9 + j];
        bf8_t A0[9];
#pragma unroll
        for (int j = 0; j < 9; ++j) {
            bf8_t a = {};
            if (idx[j] >= 0) {
                const us8_t raw = *(const us8_t*)(hb + (size_t)idx[j] * CC + q * 8);
                us8_t o;
#pragma unroll
                for (int e = 0; e < 8; ++e)
                    o[e] = f2bf(fmaxf(bf2f(raw[e]) * sc_[e] + sh_[e], 0.f));
                a = __builtin_bit_cast(bf8_t, o);
            }
            A0[j] = a;
        }
#pragma unroll
        for (int j = 0; j < 9; ++j) {
            const unsigned short* wk = Wt + (kb * 9 + j) * (CC * CC) + q * 8;
            const bf8_t w0 = *(const bf8_t*)(wk + m * CC);
            const bf8_t w1 = *(const bf8_t*)(wk + (m + 16) * CC);
            acc00 = __builtin_amdgcn_mfma_f32_16x16x32_bf16(A0[j], w0, acc00, 0, 0, 0);
            acc01 = __builtin_amdgcn_mfma_f32_16x16x32_bf16(A0[j], w1, acc01, 0, 0, 0);
        }
    }

    const float b0 = bias[m], b1 = bias[m + 16];
    float s0 = 0.f, q0 = 0.f, s1 = 0.f, q1 = 0.f;
    const int prow = p0 + q * 4;
#pragma unroll
    for (int r = 0; r < 4; ++r) {
        const float v0 = acc00[r] + b0;
        const float v1 = acc01[r] + b1;
        __builtin_nontemporal_store(f2bf(v0), h2b + (size_t)(prow + r) * CC + m);
        __builtin_nontemporal_store(f2bf(v1), h2b + (size_t)(prow + r) * CC + m + 16);
        s0 += v0; q0 += v0 * v0;
        s1 += v1; q1 += v1 * v1;
    }
    s0 += __shfl_down(s0, 32, 64); s0 += __shfl_down(s0, 16, 64);
    q0 += __shfl_down(q0, 32, 64); q0 += __shfl_down(q0, 16, 64);
    s1 += __shfl_down(s1, 32, 64); s1 += __shfl_down(s1, 16, 64);
    q1 += __shfl_down(q1, 32, 64); q1 += __shfl_down(q1, 16, 64);

    if (lane < 16) {
        rs[wave][m] = s0;      rq[wave][m] = q0;
        rs[wave][m + 16] = s1; rq[wave][m + 16] = q1;
    }
    __syncthreads();
    if (t < CC) {
        float ssum = 0.f, qsum = 0.f;
#pragma unroll
        for (int w = 0; w < 8; ++w) { ssum += rs[w][t]; qsum += rq[w][t]; }
        atomicAdd(&sums[t], ssum);
        atomicAdd(&sums[CC + t], qsum);
    }
}

// ---------------------------------------------------------------------------
// BN2 + residual + ReLU: read bf16 h2 + fp32 x, write final fp32 out.
// ---------------------------------------------------------------------------
__global__ __launch_bounds__(256) void bn_res_relu_kernel(
    const unsigned short* __restrict__ h2b, const float* __restrict__ sums,
    const float* __restrict__ gamma, const float* __restrict__ beta,
    const float* __restrict__ x, float* __restrict__ out)
{
    const size_t base = ((size_t)blockIdx.x * 256 + threadIdx.x) * 8;
    if (base >= (size_t)NPTS * CC) return;
    const int d0 = (int)(base & (CC - 1));   // thread-invariant (stride%32==0)
    float sc_[8], sh_[8];
#pragma unroll
    for (int j = 0; j < 8; ++j) {
        const int d = d0 + j;
        const float mean = sums[d] * (1.f / NPTS);
        const float var = sums[CC + d] * (1.f / NPTS) - mean * mean;
        const float s = gamma[d] * rsqrtf(var + EPSV);
        sc_[j] = s;
        sh_[j] = beta[d] - mean * s;
    }
    const us8_t hv = __builtin_nontemporal_load((const us8_t*)(h2b + base));
    const f4_t x0 = __builtin_nontemporal_load((const f4_t*)(x + base));
    const f4_t x1 = __builtin_nontemporal_load((const f4_t*)(x + base + 4));
    f4_t r0, r1;
#pragma unroll
    for (int j = 0; j < 8; ++j) {
        const float xv = (j < 4 ? x0[j] : x1[j - 4]);
        const float v = fmaxf(bf2f(hv[j]) * sc_[j] + sh_[j] + xv, 0.f);
        if (j < 4) r0[j] = v; else r1[j - 4] = v;
    }
    __builtin_nontemporal_store(r0, (f4_t*)(out + base));
    __builtin_nontemporal_store(r1, (f4_t*)(out + base + 4));
}

extern "C" void kernel_launch(void* const* d_in, const int* in_sizes, int n_in,
                              void* d_out, int out_size, void* d_ws, size_t ws_size,
                              hipStream_t stream) {
    const float* x   = (const float*)d_in[0];
    const float* W1  = (const float*)d_in[1];
    const float* b1  = (const float*)d_in[2];
    const float* g1  = (const float*)d_in[3];
    const float* be1 = (const float*)d_in[4];
    const float* W2  = (const float*)d_in[5];
    const float* b2  = (const float*)d_in[6];
    const float* g2  = (const float*)d_in[7];
    const float* be2 = (const float*)d_in[8];
    const int* nbr1  = (const int*)d_in[9];
    const int* mask1 = (const int*)d_in[10];
    const int* nbr2  = (const int*)d_in[11];
    const int* mask2 = (const int*)d_in[12];

    float* out = (float*)d_out;

    // workspace (~25.8 MB): sums(256f) | xbuf bf16 | Wt1 | Wt2.
    // h1 (bf16) lives in the FIRST HALF of d_out (scratch until the final
    // kernel overwrites d_out with fp32 results); h2 (bf16) reuses xbuf.
    float* sums          = (float*)d_ws;
    unsigned short* xbuf = (unsigned short*)((char*)d_ws + 1024);
    unsigned short* Wt1  = xbuf + (size_t)NPTS * CC;
    unsigned short* Wt2  = Wt1 + KK * CC * CC;
    unsigned short* h1b  = (unsigned short*)out;   // 25.6 MB of 51.2 MB
    unsigned short* h2b  = xbuf;                   // xb dead after conv1

    const int cvt_blocks = WBLOCKS + (NPTS * CC / 8 + 255) / 256; // 216 + 6250

    cvt_all<<<cvt_blocks, 256, 0, stream>>>(x, W1, W2, xbuf, Wt1, Wt2, sums);
    // conv1: xb -> h1 bf16 (+ BN1 stats in sums[0:64])
    conv1_mfma<<<NPTS / 128, 512, 0, stream>>>(xbuf, Wt1, b1, nbr1, mask1, h1b, sums);
    // conv2: BN1+ReLU fused into gather; -> h2 bf16 (+ BN2 stats sums[64:128])
    conv2_mfma<<<NPTS / 128, 512, 0, stream>>>(h1b, Wt2, b2, g1, be1, sums,
                                               nbr2, mask2, h2b, sums + 64);
    // BN2 + residual + ReLU -> final fp32 out
    bn_res_relu_kernel<<<(NPTS * CC / 8 + 255) / 256, 256, 0, stream>>>(
        h2b, sums + 64, g2, be2, x, out);
}

// Round 7
// 500.623 us; speedup vs baseline: 1.0590x; 1.0590x over previous
//
#include <hip/hip_runtime.h>

#define NPTS 400000
#define KK 27
#define CC 32
#define EPSV 1e-5f
#define LSTRIDE 29   // 27 k's padded to odd stride -> conflict-free LDS access

using bf8_t = __attribute__((ext_vector_type(8))) __bf16;
using f4_t  = __attribute__((ext_vector_type(4))) float;
using us8_t = __attribute__((ext_vector_type(8))) unsigned short;

__device__ __forceinline__ unsigned short f2bf(float f) {
    unsigned int u = __float_as_uint(f);
    u += 0x7FFF + ((u >> 16) & 1u);   // RNE to bf16
    return (unsigned short)(u >> 16);
}
__device__ __forceinline__ float bf2f(unsigned short s) {
    return __uint_as_float((unsigned)s << 16);
}

// ---------------------------------------------------------------------------
// Fused conversions: blocks [0,216) transpose W1|W2 -> bf16 [k][d][c];
// remaining blocks convert x -> bf16 rows. Block 0 zeroes the BN-stat slots.
// ---------------------------------------------------------------------------
#define WBLOCKS 216  // 2*27*32*32 / 256
__global__ __launch_bounds__(256) void cvt_all(
    const float* __restrict__ x,
    const float* __restrict__ W1, const float* __restrict__ W2,
    unsigned short* __restrict__ xb,
    unsigned short* __restrict__ Wt1, unsigned short* __restrict__ Wt2,
    float* __restrict__ sums)
{
    const int bid = blockIdx.x;
    if (bid < WBLOCKS) {
        if (bid == 0) sums[threadIdx.x] = 0.f;   // zero 256 stat slots
        const int id = bid * 256 + threadIdx.x;          // < 55296
        const int which = id >= KK * CC * CC;
        const int t = which ? id - KK * CC * CC : id;
        const int k = t >> 10, d = (t >> 5) & 31, c = t & 31;
        const float* W = which ? W2 : W1;
        unsigned short* Wt = which ? Wt2 : Wt1;
        Wt[t] = f2bf(W[k * 1024 + c * CC + d]);
        return;
    }
    const size_t base = ((size_t)(bid - WBLOCKS) * 256 + threadIdx.x) * 8;
    if (base >= (size_t)NPTS * CC) return;
    // x single-use here -> nt (keep L2 for gather sets; round-3: -10% on conv)
    const f4_t v0 = __builtin_nontemporal_load((const f4_t*)(x + base));
    const f4_t v1 = __builtin_nontemporal_load((const f4_t*)(x + base + 4));
    us8_t o;
#pragma unroll
    for (int j = 0; j < 8; ++j) o[j] = f2bf(j < 4 ? v0[j] : v1[j - 4]);
    *(us8_t*)(xb + base) = o;   // re-read by conv1 gathers: keep cached
}

// ---------------------------------------------------------------------------
// Gather-GEMM via MFMA: bf16 rows in -> bf16 rows out (+ BN stats from fp32).
// Used for BOTH convs. Gather loop is byte-identical to the round-3 winner.
// Established rounds 0-6: conv time is set by the random-gather L2-miss line
// service rate (~2.3 TB/s, L3-resident set) — insensitive to occupancy
// (38/60/74%: +-3%), ILP depth, weight volume (2x: +0%); nt on single-use
// streams -10% (L2 pollution); ZERO extra VALU tolerated in the gather path
// (round 6: per-gather BN = 13.5x amplification, VALUBusy 37%, +57 us).
// ---------------------------------------------------------------------------
__global__ __launch_bounds__(512, 6) void conv_mfma(
    const unsigned short* __restrict__ xb,   // [N][32] bf16 input rows
    const unsigned short* __restrict__ Wt,   // [27][32(d)][32(c)] bf16
    const float* __restrict__ bias,          // [32]
    const int* __restrict__ nbr,             // [N][27]
    const int* __restrict__ mask,            // [N][27] int32 0/1
    unsigned short* __restrict__ hb,         // [N][32] bf16 out (scratch)
    float* __restrict__ sums)                // [64]: sum, sumsq (fp32 pre-quant)
{
    __shared__ int lidx[128 * LSTRIDE];      // 14848 B
    __shared__ float rs[8][CC], rq[8][CC];   // 2048 B

    const int t = threadIdx.x;
    const int P0 = blockIdx.x * 128;         // 3125 blocks * 128 = N exactly

    const int* nb = nbr + (size_t)P0 * KK;
    const int* mb = mask + (size_t)P0 * KK;
    for (int i = t; i < 128 * KK; i += 512) {
        const int p = i / KK;
        const int k = i - p * KK;
        const int nv = __builtin_nontemporal_load(nb + i);
        const int mv = __builtin_nontemporal_load(mb + i);
        lidx[p * LSTRIDE + k] = mv ? nv : -1;
    }
    __syncthreads();

    const int wave = t >> 6;                 // 0..7
    const int lane = t & 63;
    const int m = lane & 15;
    const int q = lane >> 4;
    const int p0 = P0 + wave * 16;

    const int* rowA = lidx + (wave * 16 + m) * LSTRIDE;

    f4_t acc00 = {}, acc01 = {};

#pragma unroll
    for (int kb = 0; kb < 3; ++kb) {
        int idx[9];
#pragma unroll
        for (int j = 0; j < 9; ++j) idx[j] = rowA[kb * 9 + j];
        bf8_t A0[9];
#pragma unroll
        for (int j = 0; j < 9; ++j) {
            bf8_t t0 = {};
            if (idx[j] >= 0) t0 = *(const bf8_t*)(xb + (size_t)idx[j] * CC + q * 8);
            A0[j] = t0;
        }
#pragma unroll
        for (int j = 0; j < 9; ++j) {
            const unsigned short* wk = Wt + (kb * 9 + j) * (CC * CC) + q * 8;
            const bf8_t w0 = *(const bf8_t*)(wk + m * CC);          // d 0..15
            const bf8_t w1 = *(const bf8_t*)(wk + (m + 16) * CC);   // d 16..31
            acc00 = __builtin_amdgcn_mfma_f32_16x16x32_bf16(A0[j], w0, acc00, 0, 0, 0);
            acc01 = __builtin_amdgcn_mfma_f32_16x16x32_bf16(A0[j], w1, acc01, 0, 0, 0);
        }
    }

    // epilogue: D[row=(q*4+r)][col=m] -> point p0+q*4+r, channel m (+16)
    const float b0 = bias[m], b1 = bias[m + 16];
    float s0 = 0.f, q0 = 0.f, s1 = 0.f, q1 = 0.f;
    const int prow = p0 + q * 4;
#pragma unroll
    for (int r = 0; r < 4; ++r) {
        const float v0 = acc00[r] + b0;
        const float v1 = acc01[r] + b1;
        // stats from fp32 (pre-quantization); h stored bf16 nt (single
        // consumer downstream; protect the gather set in L2 now)
        __builtin_nontemporal_store(f2bf(v0), hb + (size_t)(prow + r) * CC + m);
        __builtin_nontemporal_store(f2bf(v1), hb + (size_t)(prow + r) * CC + m + 16);
        s0 += v0; q0 += v0 * v0;
        s1 += v1; q1 += v1 * v1;
    }
    s0 += __shfl_down(s0, 32, 64); s0 += __shfl_down(s0, 16, 64);
    q0 += __shfl_down(q0, 32, 64); q0 += __shfl_down(q0, 16, 64);
    s1 += __shfl_down(s1, 32, 64); s1 += __shfl_down(s1, 16, 64);
    q1 += __shfl_down(q1, 32, 64); q1 += __shfl_down(q1, 16, 64);

    if (lane < 16) {
        rs[wave][m] = s0;      rq[wave][m] = q0;
        rs[wave][m + 16] = s1; rq[wave][m + 16] = q1;
    }
    __syncthreads();
    if (t < CC) {
        float ssum = 0.f, qsum = 0.f;
#pragma unroll
        for (int w = 0; w < 8; ++w) { ssum += rs[w][t]; qsum += rq[w][t]; }
        atomicAdd(&sums[t], ssum);
        atomicAdd(&sums[CC + t], qsum);
    }
}

// ---------------------------------------------------------------------------
// BN1 + ReLU: bf16 h1 in (nt), bf16 a1 out (cached — conv2 gathers it next).
// Per-element ONCE (round-6 lesson: never per-gather).
// ---------------------------------------------------------------------------
__global__ __launch_bounds__(256) void bn_relu_bf16(
    const unsigned short* __restrict__ h1b, const float* __restrict__ sums,
    const float* __restrict__ gamma, const float* __restrict__ beta,
    unsigned short* __restrict__ a1b)
{
    const size_t base = ((size_t)blockIdx.x * 256 + threadIdx.x) * 8;
    if (base >= (size_t)NPTS * CC) return;
    const int d0 = (int)(base & (CC - 1));   // thread-invariant (stride%32==0)
    float sc_[8], sh_[8];
#pragma unroll
    for (int j = 0; j < 8; ++j) {
        const int d = d0 + j;
        const float mean = sums[d] * (1.f / NPTS);
        const float var = sums[CC + d] * (1.f / NPTS) - mean * mean;
        const float s = gamma[d] * rsqrtf(var + EPSV);
        sc_[j] = s;
        sh_[j] = beta[d] - mean * s;
    }
    const us8_t hv = __builtin_nontemporal_load((const us8_t*)(h1b + base));
    us8_t o;
#pragma unroll
    for (int j = 0; j < 8; ++j)
        o[j] = f2bf(fmaxf(bf2f(hv[j]) * sc_[j] + sh_[j], 0.f));
    *(us8_t*)(a1b + base) = o;
}

// ---------------------------------------------------------------------------
// BN2 + residual + ReLU: read bf16 h2 + fp32 x, write final fp32 out.
// ---------------------------------------------------------------------------
__global__ __launch_bounds__(256) void bn_res_relu_kernel(
    const unsigned short* __restrict__ h2b, const float* __restrict__ sums,
    const float* __restrict__ gamma, const float* __restrict__ beta,
    const float* __restrict__ x, float* __restrict__ out)
{
    const size_t base = ((size_t)blockIdx.x * 256 + threadIdx.x) * 8;
    if (base >= (size_t)NPTS * CC) return;
    const int d0 = (int)(base & (CC - 1));
    float sc_[8], sh_[8];
#pragma unroll
    for (int j = 0; j < 8; ++j) {
        const int d = d0 + j;
        const float mean = sums[d] * (1.f / NPTS);
        const float var = sums[CC + d] * (1.f / NPTS) - mean * mean;
        const float s = gamma[d] * rsqrtf(var + EPSV);
        sc_[j] = s;
        sh_[j] = beta[d] - mean * s;
    }
    const us8_t hv = __builtin_nontemporal_load((const us8_t*)(h2b + base));
    const f4_t x0 = __builtin_nontemporal_load((const f4_t*)(x + base));
    const f4_t x1 = __builtin_nontemporal_load((const f4_t*)(x + base + 4));
    f4_t r0, r1;
#pragma unroll
    for (int j = 0; j < 8; ++j) {
        const float xv = (j < 4 ? x0[j] : x1[j - 4]);
        const float v = fmaxf(bf2f(hv[j]) * sc_[j] + sh_[j] + xv, 0.f);
        if (j < 4) r0[j] = v; else r1[j - 4] = v;
    }
    __builtin_nontemporal_store(r0, (f4_t*)(out + base));
    __builtin_nontemporal_store(r1, (f4_t*)(out + base + 4));
}

extern "C" void kernel_launch(void* const* d_in, const int* in_sizes, int n_in,
                              void* d_out, int out_size, void* d_ws, size_t ws_size,
                              hipStream_t stream) {
    const float* x   = (const float*)d_in[0];
    const float* W1  = (const float*)d_in[1];
    const float* b1  = (const float*)d_in[2];
    const float* g1  = (const float*)d_in[3];
    const float* be1 = (const float*)d_in[4];
    const float* W2  = (const float*)d_in[5];
    const float* b2  = (const float*)d_in[6];
    const float* g2  = (const float*)d_in[7];
    const float* be2 = (const float*)d_in[8];
    const int* nbr1  = (const int*)d_in[9];
    const int* mask1 = (const int*)d_in[10];
    const int* nbr2  = (const int*)d_in[11];
    const int* mask2 = (const int*)d_in[12];

    float* out = (float*)d_out;

    // Buffer plan (all intermediates bf16, 25.6 MB each; no extra memory):
    //   xb  = ws.xbuf                     (conv1 gather source)
    //   h1b = d_out lower half            (conv1 out; dead after bn1)
    //   a1b = d_out upper half            (bn1 out; conv2 gather source)
    //   h2b = ws.xbuf  (xb dead)          (conv2 out; final reads it)
    //   final: reads h2b + x, overwrites all of d_out with fp32 (a1b dead)
    float* sums          = (float*)d_ws;
    unsigned short* xbuf = (unsigned short*)((char*)d_ws + 1024);
    unsigned short* Wt1  = xbuf + (size_t)NPTS * CC;
    unsigned short* Wt2  = Wt1 + KK * CC * CC;
    unsigned short* h1b  = (unsigned short*)out;              // lower 25.6 MB
    unsigned short* a1b  = (unsigned short*)out + (size_t)NPTS * CC; // upper
    unsigned short* h2b  = xbuf;

    const int cvt_blocks = WBLOCKS + (NPTS * CC / 8 + 255) / 256; // 216 + 6250
    const int ew_blocks  = (NPTS * CC / 8 + 255) / 256;           // 6250

    cvt_all<<<cvt_blocks, 256, 0, stream>>>(x, W1, W2, xbuf, Wt1, Wt2, sums);
    // conv1: xb -> h1 bf16 (+ BN1 stats in sums[0:64])
    conv_mfma<<<NPTS / 128, 512, 0, stream>>>(xbuf, Wt1, b1, nbr1, mask1, h1b, sums);
    // BN1 + ReLU: h1 bf16 -> a1 bf16
    bn_relu_bf16<<<ew_blocks, 256, 0, stream>>>(h1b, sums, g1, be1, a1b);
    // conv2: a1 -> h2 bf16 (+ BN2 stats in sums[64:128])
    conv_mfma<<<NPTS / 128, 512, 0, stream>>>(a1b, Wt2, b2, nbr2, mask2, h2b, sums + 64);
    // BN2 + residual + ReLU -> final fp32 out
    bn_res_relu_kernel<<<ew_blocks, 256, 0, stream>>>(h2b, sums + 64, g2, be2, x, out);
}